// Round 7
// baseline (198.983 us; speedup 1.0000x reference)
//
#include <hip/hip_runtime.h>

#define NN 50000
#define NE 1600000
#define DF 128
#define NB 250      // coarse buckets
#define BSZ 200     // dst nodes per bucket  (NB*BSZ == NN)
#define NWG 256     // partition workgroups
#define CHK 6250    // edges per partition wg (NWG*CHK == NE)
#define NBN 12500   // norm blocks (4 waves each -> NN waves)

static __device__ __forceinline__ float bflo(unsigned int u) {
    unsigned int v = u << 16; float f; __builtin_memcpy(&f, &v, 4); return f;
}
static __device__ __forceinline__ float bfhi(unsigned int u) {
    unsigned int v = u & 0xFFFF0000u; float f; __builtin_memcpy(&f, &v, 4); return f;
}
static __device__ __forceinline__ unsigned int f2bf(float f) {   // RNE, low 16 bits
    unsigned int u; __builtin_memcpy(&u, &f, 4);
    u += 0x7FFFu + ((u >> 16) & 1u);
    return u >> 16;
}

// Block-wide exclusive scan of one value per thread (values beyond n must be 0).
// Wave-scan (6 shfl_up) + cross-wave offsets: 2 barriers total.
static __device__ __forceinline__ int block_excl_scan(int v, int t, int* wsum4) {
    int lane = t & 63, wv = t >> 6;
    int s = v;
    #pragma unroll
    for (int off = 1; off < 64; off <<= 1) {
        int u = __shfl_up(s, off);
        if (lane >= off) s += u;
    }
    if (lane == 63) wsum4[wv] = s;
    __syncthreads();
    int add = 0;
    #pragma unroll
    for (int w = 0; w < 4; ++w) add += (w < wv) ? wsum4[w] : 0;
    __syncthreads();
    return s + add - v;      // exclusive
}

// ---------------------------------------------------------------------------
// K1 (fused, disjoint block ranges):
//  blocks [0,NBN):       one wave per node: xn_bf = bf16(x * rsqrt(max(ss,eps^2))),
//                        norm = ||x||. Softmax later shifts by the constant
//                        |beta| (exact by shift-invariance; self-loop keeps
//                        every denominator >= exp(-2|beta|) > 0).
//  blocks [NBN,NBN+NWG): per-wg LDS histogram of coarse dst buckets,
//                        written COALESCED as whist[wg][bucket].
// ---------------------------------------------------------------------------
__global__ void k_norm_count(const float* __restrict__ x,
                             const int* __restrict__ ei,
                             unsigned int* __restrict__ xn_bf,
                             float* __restrict__ norm,
                             int* __restrict__ whist) {
    if (blockIdx.x < NBN) {
        int wave = (blockIdx.x * 256 + threadIdx.x) >> 6;
        int lane = threadIdx.x & 63;
        float2 v = ((const float2*)(x + (size_t)wave * DF))[lane];
        float ss = v.x * v.x + v.y * v.y;
        #pragma unroll
        for (int m = 1; m < 64; m <<= 1) ss += __shfl_xor(ss, m);
        float rinv = rsqrtf(fmaxf(ss, 1e-24f));
        xn_bf[(size_t)wave * 64 + lane] = (f2bf(v.y * rinv) << 16) | f2bf(v.x * rinv);
        if (lane == 0) norm[wave] = ss * rinv;
    } else {
        __shared__ int h[NB];
        int wg = blockIdx.x - NBN, t = threadIdx.x;
        if (t < NB) h[t] = 0;
        __syncthreads();
        const int* dstp = ei + NE + wg * CHK;
        for (int i = t; i < CHK; i += 256) atomicAdd(&h[dstp[i] / BSZ], 1);
        __syncthreads();
        if (t < NB) whist[wg * NB + t] = h[t];     // coalesced, full lines
    }
}

// K2: partition edges into bucket-sorted packed records (local_dst<<16 | src).
// Each wg recomputes bucket bases + its own within-bucket offsets by reading
// the whole whist (64K ints, coalesced, L2-resident) — no scan dispatch.
__global__ void k_part(const int* __restrict__ ei, const int* __restrict__ whist,
                       unsigned int* __restrict__ pairs) {
    __shared__ int wsum4[4];
    __shared__ int cur[NB];
    int wg = blockIdx.x, t = threadIdx.x;
    int total = 0, pre = 0;
    if (t < NB) {
        for (int w = 0; w < NWG; ++w) {
            int v = whist[w * NB + t];             // lanes read consecutive ints
            total += v;
            pre += (w < wg) ? v : 0;
        }
    }
    int base = block_excl_scan(total, t, wsum4);
    if (t < NB) cur[t] = base + pre;
    __syncthreads();
    int c0 = wg * CHK;
    for (int i = t; i < CHK; i += 256) {
        int src = ei[c0 + i];
        int dst = ei[NE + c0 + i];
        int b = dst / BSZ;
        int pos = atomicAdd(&cur[b], 1);
        pairs[pos] = ((unsigned int)(dst - b * BSZ) << 16) | (unsigned int)src;
    }
}

// K3: one wg per bucket: recompute bucket base from whist, LDS hist over its
// 200 dst, LDS scan -> row_ptr, then LDS-cursor fill of col. col packs the
// source-row norm (bf16) in the high 16 bits so the gather needs no norm load.
__global__ void k_build(const unsigned int* __restrict__ pairs,
                        const int* __restrict__ whist,
                        const float* __restrict__ norm,
                        int* __restrict__ row_ptr, unsigned int* __restrict__ col) {
    __shared__ int wsum4[4];
    __shared__ int h[BSZ];
    __shared__ int sbase, send;
    int b = blockIdx.x, t = threadIdx.x;
    int total = 0;
    if (t < NB) {
        for (int w = 0; w < NWG; ++w) total += whist[w * NB + t];
    }
    int base_t = block_excl_scan(total, t, wsum4);
    if (t == b) { sbase = base_t; send = base_t + total; }
    if (t < BSZ) h[t] = 0;
    __syncthreads();
    int base = sbase, end = send;
    for (int i = base + t; i < end; i += 256) atomicAdd(&h[pairs[i] >> 16], 1);
    __syncthreads();
    int own = (t < BSZ) ? h[t] : 0;
    __syncthreads();                                   // h reads done before reuse
    int excl = block_excl_scan(own, t, wsum4);
    if (t < BSZ) {
        row_ptr[b * BSZ + t] = base + excl;
        h[t] = base + excl;                            // fill cursor
    }
    if (b == 0 && t == 0) row_ptr[NN] = NE;
    __syncthreads();
    for (int i = base + t; i < end; i += 256) {
        unsigned int p = pairs[i];
        unsigned int src = p & 0xFFFFu;
        int pos = atomicAdd(&h[p >> 16], 1);
        col[pos] = (f2bf(norm[src]) << 16) | src;
    }
}

// K4: one wave per dst node, 4 groups x 16 lanes. Manual 2-deep software
// pipeline: col prefetched two iterations ahead, src row one ahead, so a row
// gather is always in flight while computing the current edge.
__global__ void k_gather(const unsigned int* __restrict__ xn_bf,
                         const float* __restrict__ norm,
                         const int* __restrict__ row_ptr,
                         const unsigned int* __restrict__ col,
                         const float* __restrict__ beta_p,
                         float* __restrict__ out) {
    int wave = (blockIdx.x * blockDim.x + threadIdx.x) >> 6;
    int lane = threadIdx.x & 63;
    if (wave >= NN) return;
    int j = lane & 15;
    int g = lane >> 4;
    float beta = beta_p[0];
    float c = -fabsf(beta);

    uint4 du = ((const uint4*)(xn_bf + (size_t)wave * 64))[j];
    float xd[8];
    #pragma unroll
    for (int q = 0; q < 4; ++q) {
        unsigned int u = (&du.x)[q];
        xd[2 * q]     = bflo(u);
        xd[2 * q + 1] = bfhi(u);
    }

    float acc[8] = {0.f, 0.f, 0.f, 0.f, 0.f, 0.f, 0.f, 0.f};
    float ssum = 0.f;
    int b0 = row_ptr[wave], b1 = row_ptr[wave + 1];

    int k = b0 + g;
    int kcA = (k     < b1) ? k     : 0;     // clamped safe indices (col[0] always valid)
    int kcB = (k + 4 < b1) ? k + 4 : 0;
    unsigned int pA = col[kcA];
    unsigned int pB = col[kcB];
    uint4 suA = ((const uint4*)(xn_bf + (size_t)(pA & 0xFFFFu) * 64))[j];

    for (; k < b1; k += 4) {
        uint4 suB = ((const uint4*)(xn_bf + (size_t)(pB & 0xFFFFu) * 64))[j];
        int kcC = (k + 8 < b1) ? k + 8 : 0;
        unsigned int pC = col[kcC];

        float nrm = bfhi(pA);
        float xs[8];
        #pragma unroll
        for (int q = 0; q < 4; ++q) {
            unsigned int u = (&suA.x)[q];
            xs[2 * q]     = bflo(u);
            xs[2 * q + 1] = bfhi(u);
        }
        float dot = 0.f;
        #pragma unroll
        for (int q = 0; q < 8; ++q) dot = fmaf(xd[q], xs[q], dot);
        dot += __shfl_xor(dot, 1);
        dot += __shfl_xor(dot, 2);
        dot += __shfl_xor(dot, 4);
        dot += __shfl_xor(dot, 8);
        float e = __expf(fmaf(beta, dot, c));
        ssum += e;
        float w = e * nrm;
        #pragma unroll
        for (int q = 0; q < 8; ++q) acc[q] = fmaf(w, xs[q], acc[q]);

        pA = pB; pB = pC; suA = suB;
    }

    ssum += __shfl_xor(ssum, 16);
    ssum += __shfl_xor(ssum, 32);
    #pragma unroll
    for (int q = 0; q < 8; ++q) {
        acc[q] += __shfl_xor(acc[q], 16);
        acc[q] += __shfl_xor(acc[q], 32);
    }

    // self-loop (cos = 1): e_self = exp(beta - |beta|), message e_self * x_dst
    float e_self = __expf(beta + c);
    ssum += e_self;
    float wsl = e_self * norm[wave];
    #pragma unroll
    for (int q = 0; q < 8; ++q) acc[q] = fmaf(wsl, xd[q], acc[q]);

    if (g == 0) {
        float inv = 1.0f / ssum;
        float4 o0, o1;
        o0.x = fmaxf(0.f, acc[0] * inv); o0.y = fmaxf(0.f, acc[1] * inv);
        o0.z = fmaxf(0.f, acc[2] * inv); o0.w = fmaxf(0.f, acc[3] * inv);
        o1.x = fmaxf(0.f, acc[4] * inv); o1.y = fmaxf(0.f, acc[5] * inv);
        o1.z = fmaxf(0.f, acc[6] * inv); o1.w = fmaxf(0.f, acc[7] * inv);
        float4* op = (float4*)(out + (size_t)wave * DF + 8 * j);
        op[0] = o0;
        op[1] = o1;
    }
}

extern "C" void kernel_launch(void* const* d_in, const int* in_sizes, int n_in,
                              void* d_out, int out_size, void* d_ws, size_t ws_size,
                              hipStream_t stream) {
    const float* x    = (const float*)d_in[0];   // fp32 [NN*DF]
    const float* beta = (const float*)d_in[1];   // fp32 [1]
    const int*   ei   = (const int*)d_in[2];     // int32 [2*NE]
    float*       out  = (float*)d_out;           // fp32 [NN*DF]

    // workspace layout (bytes), total ~26.3 MiB:
    char* ws = (char*)d_ws;
    unsigned int* xn_bf = (unsigned int*)ws;                  // 12,800,000
    float* norm    = (float*)(ws + 12800000);                 //    200,000
    int*   whist   = (int*)  (ws + 13000000);                 // NWG*NB*4 = 256,000
    int*   row_ptr = (int*)  (ws + 13256000);                 // (NN+1)*4 = 200,004
    unsigned int* pairs = (unsigned int*)(ws + 13456016);     // NE*4 = 6,400,000
    unsigned int* col   = (unsigned int*)(ws + 19856016);     // NE*4 = 6,400,000

    k_norm_count<<<NBN + NWG, 256, 0, stream>>>(x, ei, xn_bf, norm, whist);
    k_part      <<<NWG,       256, 0, stream>>>(ei, whist, pairs);
    k_build     <<<NB,        256, 0, stream>>>(pairs, whist, norm, row_ptr, col);
    k_gather    <<<(NN * 64 + 255) / 256, 256, 0, stream>>>(xn_bf, norm, row_ptr, col, beta, out);
}

// Round 8
// 177.538 us; speedup vs baseline: 1.1208x; 1.1208x over previous
//
#include <hip/hip_runtime.h>

#define NN 50000
#define NE 1600000
#define DF 128
#define NB 250      // coarse buckets
#define BSZ 200     // dst nodes per bucket  (NB*BSZ == NN)
#define NWG 256     // partition workgroups
#define CHK 6250    // edges per partition wg (NWG*CHK == NE)
#define NBN 12500   // norm blocks (4 waves each -> NN waves)

static __device__ __forceinline__ float bflo(unsigned int u) {
    unsigned int v = u << 16; float f; __builtin_memcpy(&f, &v, 4); return f;
}
static __device__ __forceinline__ float bfhi(unsigned int u) {
    unsigned int v = u & 0xFFFF0000u; float f; __builtin_memcpy(&f, &v, 4); return f;
}
static __device__ __forceinline__ unsigned int f2bf(float f) {   // RNE, low 16 bits
    unsigned int u; __builtin_memcpy(&u, &f, 4);
    u += 0x7FFFu + ((u >> 16) & 1u);
    return u >> 16;
}

// Block-wide exclusive scan of one value per thread. Wave-scan (shfl_up) +
// cross-wave offsets: 2 barriers total.
static __device__ __forceinline__ int block_excl_scan(int v, int t, int* wsum4) {
    int lane = t & 63, wv = t >> 6;
    int s = v;
    #pragma unroll
    for (int off = 1; off < 64; off <<= 1) {
        int u = __shfl_up(s, off);
        if (lane >= off) s += u;
    }
    if (lane == 63) wsum4[wv] = s;
    __syncthreads();
    int add = 0;
    #pragma unroll
    for (int w = 0; w < 4; ++w) add += (w < wv) ? wsum4[w] : 0;
    __syncthreads();
    return s + add - v;      // exclusive
}

// ---------------------------------------------------------------------------
// K1 (fused, disjoint block ranges):
//  blocks [0,NBN):       one wave per node: xn_bf = bf16(x * rsqrt(max(ss,eps^2))),
//                        norm = ||x||. Softmax later shifts by the constant
//                        |beta| (exact by shift-invariance; self-loop keeps
//                        every denominator >= exp(-2|beta|) > 0).
//  blocks [NBN,NBN+NWG): per-wg LDS histogram of coarse dst buckets,
//                        written COALESCED as whist[wg][bucket].
// ---------------------------------------------------------------------------
__global__ void k_norm_count(const float* __restrict__ x,
                             const int* __restrict__ ei,
                             unsigned int* __restrict__ xn_bf,
                             float* __restrict__ norm,
                             int* __restrict__ whist) {
    if (blockIdx.x < NBN) {
        int wave = (blockIdx.x * 256 + threadIdx.x) >> 6;
        int lane = threadIdx.x & 63;
        float2 v = ((const float2*)(x + (size_t)wave * DF))[lane];
        float ss = v.x * v.x + v.y * v.y;
        #pragma unroll
        for (int m = 1; m < 64; m <<= 1) ss += __shfl_xor(ss, m);
        float rinv = rsqrtf(fmaxf(ss, 1e-24f));
        xn_bf[(size_t)wave * 64 + lane] = (f2bf(v.y * rinv) << 16) | f2bf(v.x * rinv);
        if (lane == 0) norm[wave] = ss * rinv;
    } else {
        __shared__ int h[NB];
        int wg = blockIdx.x - NBN, t = threadIdx.x;
        if (t < NB) h[t] = 0;
        __syncthreads();
        const int* dstp = ei + NE + wg * CHK;
        for (int i = t; i < CHK; i += 256) atomicAdd(&h[dstp[i] / BSZ], 1);
        __syncthreads();
        if (t < NB) whist[wg * NB + t] = h[t];     // coalesced, full lines
    }
}

// K2: per-bucket exclusive scan across wg counts. Block b: thread t holds
// whist[t][b]; block-scan; write back exclusive offsets; btotal[b] = total.
// Only 64K scattered ints total — trivial.
__global__ void k_scan(int* __restrict__ whist, int* __restrict__ btotal) {
    __shared__ int wsum4[4];
    int b = blockIdx.x, t = threadIdx.x;
    int v = whist[t * NB + b];
    int excl = block_excl_scan(v, t, wsum4);
    whist[t * NB + b] = excl;
    if (t == NWG - 1) btotal[b] = excl + v;
}

// K3: partition edges into bucket-sorted packed records (local_dst<<16 | src).
// Bucket bases from a 250-int LDS scan of btotal; within-bucket offset from
// the pre-scanned whist row (coalesced). LDS cursors only — no global atomics.
__global__ void k_part(const int* __restrict__ ei, const int* __restrict__ whist,
                       const int* __restrict__ btotal, unsigned int* __restrict__ pairs) {
    __shared__ int wsum4[4];
    __shared__ int cur[NB];
    int wg = blockIdx.x, t = threadIdx.x;
    int v = (t < NB) ? btotal[t] : 0;
    int base = block_excl_scan(v, t, wsum4);
    if (t < NB) cur[t] = base + whist[wg * NB + t];
    __syncthreads();
    int c0 = wg * CHK;
    for (int i = t; i < CHK; i += 256) {
        int src = ei[c0 + i];
        int dst = ei[NE + c0 + i];
        int b = dst / BSZ;
        int pos = atomicAdd(&cur[b], 1);
        pairs[pos] = ((unsigned int)(dst - b * BSZ) << 16) | (unsigned int)src;
    }
}

// K4: one wg per bucket: bucket base from btotal scan, LDS hist over its 200
// dst, LDS scan -> row_ptr, then LDS-cursor fill of col. col packs the source
// norm (bf16) in the high 16 bits so the gather needs no separate norm load.
__global__ void k_build(const unsigned int* __restrict__ pairs,
                        const int* __restrict__ btotal,
                        const float* __restrict__ norm,
                        int* __restrict__ row_ptr, unsigned int* __restrict__ col) {
    __shared__ int wsum4[4];
    __shared__ int h[BSZ];
    __shared__ int sbase, send;
    int b = blockIdx.x, t = threadIdx.x;
    int v = (t < NB) ? btotal[t] : 0;
    int base_t = block_excl_scan(v, t, wsum4);
    if (t == b) { sbase = base_t; send = base_t + v; }
    if (t < BSZ) h[t] = 0;
    __syncthreads();
    int base = sbase, end = send;
    for (int i = base + t; i < end; i += 256) atomicAdd(&h[pairs[i] >> 16], 1);
    __syncthreads();
    int own = (t < BSZ) ? h[t] : 0;
    __syncthreads();                                   // h reads done before reuse
    int excl = block_excl_scan(own, t, wsum4);
    if (t < BSZ) {
        row_ptr[b * BSZ + t] = base + excl;
        h[t] = base + excl;                            // fill cursor
    }
    if (b == 0 && t == 0) row_ptr[NN] = NE;
    __syncthreads();
    for (int i = base + t; i < end; i += 256) {
        unsigned int p = pairs[i];
        unsigned int src = p & 0xFFFFu;
        int pos = atomicAdd(&h[p >> 16], 1);
        col[pos] = (f2bf(norm[src]) << 16) | src;
    }
}

// K5: one wave per dst node, 4 groups x 16 lanes. 2-edge software pipeline:
// two src rows in flight per group (edges k, k+4; stride 8), cols prefetched
// a full stage ahead. Invalid second edge masked by zeroing e.
__global__ void k_gather(const unsigned int* __restrict__ xn_bf,
                         const float* __restrict__ norm,
                         const int* __restrict__ row_ptr,
                         const unsigned int* __restrict__ col,
                         const float* __restrict__ beta_p,
                         float* __restrict__ out) {
    int wave = (blockIdx.x * blockDim.x + threadIdx.x) >> 6;
    int lane = threadIdx.x & 63;
    if (wave >= NN) return;
    int j = lane & 15;
    int g = lane >> 4;
    float beta = beta_p[0];
    float c = -fabsf(beta);

    uint4 du = ((const uint4*)(xn_bf + (size_t)wave * 64))[j];
    float xd[8];
    #pragma unroll
    for (int q = 0; q < 4; ++q) {
        unsigned int u = (&du.x)[q];
        xd[2 * q]     = bflo(u);
        xd[2 * q + 1] = bfhi(u);
    }

    float acc[8] = {0.f, 0.f, 0.f, 0.f, 0.f, 0.f, 0.f, 0.f};
    float ssum = 0.f;
    int b0 = row_ptr[wave], b1 = row_ptr[wave + 1];

    int k = b0 + g;
    int kA = (k     < b1) ? k     : 0;
    int kB = (k + 4 < b1) ? k + 4 : 0;
    unsigned int pA = col[kA];
    unsigned int pB = col[kB];
    uint4 rA = ((const uint4*)(xn_bf + (size_t)(pA & 0xFFFFu) * 64))[j];
    uint4 rB = ((const uint4*)(xn_bf + (size_t)(pB & 0xFFFFu) * 64))[j];

    for (; k < b1; k += 8) {
        int kC = (k +  8 < b1) ? k +  8 : 0;
        int kD = (k + 12 < b1) ? k + 12 : 0;
        unsigned int pC = col[kC];
        unsigned int pD = col[kD];
        uint4 rC = ((const uint4*)(xn_bf + (size_t)(pC & 0xFFFFu) * 64))[j];
        uint4 rD = ((const uint4*)(xn_bf + (size_t)(pD & 0xFFFFu) * 64))[j];

        // ---- edge A (always valid: k < b1) ----
        {
            float xs[8];
            #pragma unroll
            for (int q = 0; q < 4; ++q) {
                unsigned int u = (&rA.x)[q];
                xs[2 * q]     = bflo(u);
                xs[2 * q + 1] = bfhi(u);
            }
            float dot = 0.f;
            #pragma unroll
            for (int q = 0; q < 8; ++q) dot = fmaf(xd[q], xs[q], dot);
            dot += __shfl_xor(dot, 1);
            dot += __shfl_xor(dot, 2);
            dot += __shfl_xor(dot, 4);
            dot += __shfl_xor(dot, 8);
            float e = __expf(fmaf(beta, dot, c));
            ssum += e;
            float w = e * bfhi(pA);
            #pragma unroll
            for (int q = 0; q < 8; ++q) acc[q] = fmaf(w, xs[q], acc[q]);
        }
        // ---- edge B (valid iff k+4 < b1) ----
        {
            float xs[8];
            #pragma unroll
            for (int q = 0; q < 4; ++q) {
                unsigned int u = (&rB.x)[q];
                xs[2 * q]     = bflo(u);
                xs[2 * q + 1] = bfhi(u);
            }
            float dot = 0.f;
            #pragma unroll
            for (int q = 0; q < 8; ++q) dot = fmaf(xd[q], xs[q], dot);
            dot += __shfl_xor(dot, 1);
            dot += __shfl_xor(dot, 2);
            dot += __shfl_xor(dot, 4);
            dot += __shfl_xor(dot, 8);
            float e = __expf(fmaf(beta, dot, c));
            e = (k + 4 < b1) ? e : 0.f;
            ssum += e;
            float w = e * bfhi(pB);
            #pragma unroll
            for (int q = 0; q < 8; ++q) acc[q] = fmaf(w, xs[q], acc[q]);
        }
        pA = pC; pB = pD; rA = rC; rB = rD;
    }

    ssum += __shfl_xor(ssum, 16);
    ssum += __shfl_xor(ssum, 32);
    #pragma unroll
    for (int q = 0; q < 8; ++q) {
        acc[q] += __shfl_xor(acc[q], 16);
        acc[q] += __shfl_xor(acc[q], 32);
    }

    // self-loop (cos = 1): e_self = exp(beta - |beta|), message e_self * x_dst
    float e_self = __expf(beta + c);
    ssum += e_self;
    float wsl = e_self * norm[wave];
    #pragma unroll
    for (int q = 0; q < 8; ++q) acc[q] = fmaf(wsl, xd[q], acc[q]);

    if (g == 0) {
        float inv = 1.0f / ssum;
        float4 o0, o1;
        o0.x = fmaxf(0.f, acc[0] * inv); o0.y = fmaxf(0.f, acc[1] * inv);
        o0.z = fmaxf(0.f, acc[2] * inv); o0.w = fmaxf(0.f, acc[3] * inv);
        o1.x = fmaxf(0.f, acc[4] * inv); o1.y = fmaxf(0.f, acc[5] * inv);
        o1.z = fmaxf(0.f, acc[6] * inv); o1.w = fmaxf(0.f, acc[7] * inv);
        float4* op = (float4*)(out + (size_t)wave * DF + 8 * j);
        op[0] = o0;
        op[1] = o1;
    }
}

extern "C" void kernel_launch(void* const* d_in, const int* in_sizes, int n_in,
                              void* d_out, int out_size, void* d_ws, size_t ws_size,
                              hipStream_t stream) {
    const float* x    = (const float*)d_in[0];   // fp32 [NN*DF]
    const float* beta = (const float*)d_in[1];   // fp32 [1]
    const int*   ei   = (const int*)d_in[2];     // int32 [2*NE]
    float*       out  = (float*)d_out;           // fp32 [NN*DF]

    // workspace layout (bytes), total ~26.3 MiB:
    char* ws = (char*)d_ws;
    unsigned int* xn_bf = (unsigned int*)ws;                  // 12,800,000
    float* norm    = (float*)(ws + 12800000);                 //    200,000
    int*   whist   = (int*)  (ws + 13000000);                 // NWG*NB*4 = 256,000
    int*   btotal  = (int*)  (ws + 13256000);                 //      1,000 (+pad)
    int*   row_ptr = (int*)  (ws + 13257024);                 // (NN+1)*4 = 200,004
    unsigned int* pairs = (unsigned int*)(ws + 13457040);     // NE*4 = 6,400,000
    unsigned int* col   = (unsigned int*)(ws + 19857040);     // NE*4 = 6,400,000

    k_norm_count<<<NBN + NWG, 256, 0, stream>>>(x, ei, xn_bf, norm, whist);
    k_scan      <<<NB,        NWG, 0, stream>>>(whist, btotal);
    k_part      <<<NWG,       256, 0, stream>>>(ei, whist, btotal, pairs);
    k_build     <<<NB,        256, 0, stream>>>(pairs, btotal, norm, row_ptr, col);
    k_gather    <<<(NN * 64 + 255) / 256, 256, 0, stream>>>(xn_bf, norm, row_ptr, col, beta, out);
}